// Round 1
// baseline (126.032 us; speedup 1.0000x reference)
//
#include <hip/hip_runtime.h>
#include <hip/hip_bf16.h>

// MeanPooling: out[b,e,d] = (sum_l map[b,e,l]*doc[b,l,d]) / lens[b,e]
// B=16, E=256, L=4096 (=K), D=512. fp32 in/out, bf16 MFMA inside.
//
// Structure: pure-register streaming GEMM. No LDS, no barriers.
//  - 512 wave-tiles (16 b x 4 e-tiles x 8 d-tiles), each wave owns a 64x64
//    output tile = 4x4 frags of mfma_f32_16x16x32_bf16.
//  - A (map) fragments: k-contiguous -> float4 direct loads.
//  - B (doc) fragments: k-major in memory -> 8 strided dword loads per frag
//    (L2-served; per-XCD working set per k-row ~6KB so L2 absorbs re-reads).
//  - fp32 -> bf16 conversion in-register (compiler fuses to v_cvt_pk_bf16_f32).
//  - XCD-chunk swizzle: each XCD processes 2 whole batches (L2 locality).

#define NB 16
#define NE 256
#define NL 4096
#define ND 512

using f32x4  = __attribute__((ext_vector_type(4))) float;
using bf16x8 = __attribute__((ext_vector_type(8))) short;

static __device__ __forceinline__ short f2bf(float x) {
  __bf16 h = (__bf16)x;   // hardware RNE convert
  return __builtin_bit_cast(short, h);
}

__global__ __launch_bounds__(64) void mp_gemm(const float* __restrict__ doc,
                                              const float* __restrict__ emap,
                                              const float* __restrict__ lens,
                                              float* __restrict__ out) {
  int bid = (int)blockIdx.x;
  // XCD-chunk swizzle: 512 blocks, 8 XCDs -> XCD x gets logical [64x, 64x+63]
  int logical = (bid & 7) * 64 + (bid >> 3);
  int b  = logical >> 5;        // 16 batches (2 per XCD chunk)
  int et = (logical >> 3) & 3;  // 4 e-tiles of 64 rows
  int dt = logical & 7;         // 8 d-tiles of 64 cols

  int lane = (int)threadIdx.x;  // one wave per block
  int l15  = lane & 15;
  int g    = lane >> 4;         // k-group 0..3

  const float* Ab = emap + (size_t)(b * NE + et * 64) * NL;       // [64][L], k-contig
  const float* Bb = doc  + (size_t)b * NL * ND + dt * 64;         // [L][64], k-major

  f32x4 acc[4][4] = {};  // acc[m][n], each 4 fp32 (rows 4g..4g+3 of 16x16 frag)

  for (int k0 = 0; k0 < NL; k0 += 32) {
    int kA = k0 + 8 * g;  // this lane's 8 contiguous k for the K=32 MFMA
    bf16x8 af[4], bfr[4];

    // A fragments: row = 16m + l15, k = kA..kA+7 (two float4 loads)
#pragma unroll
    for (int m = 0; m < 4; ++m) {
      const float* p = Ab + (size_t)(16 * m + l15) * NL + kA;
      f32x4 lo = *reinterpret_cast<const f32x4*>(p);
      f32x4 hi = *reinterpret_cast<const f32x4*>(p + 4);
#pragma unroll
      for (int j = 0; j < 4; ++j) { af[m][j] = f2bf(lo[j]); af[m][4 + j] = f2bf(hi[j]); }
    }

    // B fragments: col = 16n + l15, k = kA+j, stride ND between k's
#pragma unroll
    for (int n = 0; n < 4; ++n) {
      const float* p = Bb + (size_t)kA * ND + (16 * n + l15);
      float t[8];
#pragma unroll
      for (int j = 0; j < 8; ++j) t[j] = p[(size_t)j * ND];
#pragma unroll
      for (int j = 0; j < 8; ++j) bfr[n][j] = f2bf(t[j]);
    }

#pragma unroll
    for (int m = 0; m < 4; ++m)
#pragma unroll
      for (int n = 0; n < 4; ++n)
        acc[m][n] = __builtin_amdgcn_mfma_f32_16x16x32_bf16(af[m], bfr[n], acc[m][n], 0, 0, 0);
  }

  // Epilogue: divide by lens and store. C/D frag: col = l15, row = 4g + i.
  const float* lb = lens + b * NE + et * 64;
  float* ob = out + (size_t)(b * NE + et * 64) * ND + dt * 64;
#pragma unroll
  for (int m = 0; m < 4; ++m) {
#pragma unroll
    for (int i = 0; i < 4; ++i) {
      int row = 16 * m + 4 * g + i;
      float inv = 1.0f / lb[row];
#pragma unroll
      for (int n = 0; n < 4; ++n)
        ob[(size_t)row * ND + 16 * n + l15] = acc[m][n][i] * inv;
    }
  }
}

extern "C" void kernel_launch(void* const* d_in, const int* in_sizes, int n_in,
                              void* d_out, int out_size, void* d_ws, size_t ws_size,
                              hipStream_t stream) {
  const float* doc  = (const float*)d_in[0];  // (B, L, D)
  const float* emap = (const float*)d_in[1];  // (B, E, L)
  const float* lens = (const float*)d_in[2];  // (B, E)
  float* out = (float*)d_out;                 // (B, E, D)
  hipLaunchKernelGGL(mp_gemm, dim3(512), dim3(64), 0, stream, doc, emap, lens, out);
}

// Round 2
// 81.528 us; speedup vs baseline: 1.5459x; 1.5459x over previous
//
#include <hip/hip_runtime.h>
#include <hip/hip_bf16.h>

// MeanPooling: out[b,e,d] = (sum_l map[b,e,l]*doc[b,l,d]) / lens[b,e]
// B=16, E=256, L=4096 (=K), D=512. fp32 in/out, bf16 MFMA inside.
//
// R2: latency-bound fix (R1: occupancy 5.7%, per-frag load serialization).
//  - Split-K x4 within a 4-wave block: all waves share one 64x64 output tile,
//    each owns K=1024; fp32 partials reduced through LDS at the end.
//    512 blocks x 256 thr = 2048 waves = 8/CU = 2/SIMD.
//  - Register ping-pong prefetch: issue iter k+1's raw fp32 loads BEFORE
//    converting/MFMA-ing iter k -> ~180cy/wave hiding window, x2 waves/SIMD.
//  - Fragment layouts identical to R1 (verified correct).

#define NB 16
#define NE 256
#define NL 4096
#define ND 512
#define KSPLIT 4
#define KPW (NL / KSPLIT)   // 1024 per wave
#define KITER (KPW / 32)    // 32 k-steps of 32

using f32x4  = __attribute__((ext_vector_type(4))) float;
using bf16x8 = __attribute__((ext_vector_type(8))) short;

static __device__ __forceinline__ short f2bf(float x) {
  __bf16 h = (__bf16)x;   // hardware RNE convert
  return __builtin_bit_cast(short, h);
}

// Load one k-step (32 wide) of A (4 frags, float4 pairs) and B (4 frags,
// 8 strided dwords each) into raw fp32 buffers.
#define LOAD_ITER(BA, BB, IT)                                                  \
  do {                                                                         \
    size_t ka_ = (size_t)(IT) * 32;                                            \
    _Pragma("unroll") for (int m_ = 0; m_ < 4; ++m_) {                         \
      const float* p_ = aPtr[m_] + ka_;                                        \
      BA[m_][0] = *reinterpret_cast<const f32x4*>(p_);                         \
      BA[m_][1] = *reinterpret_cast<const f32x4*>(p_ + 4);                     \
    }                                                                          \
    _Pragma("unroll") for (int n_ = 0; n_ < 4; ++n_) {                         \
      const float* p_ = bPtr[n_] + ka_ * ND;                                   \
      _Pragma("unroll") for (int j_ = 0; j_ < 8; ++j_)                         \
          BB[n_][j_] = p_[(size_t)j_ * ND];                                    \
    }                                                                          \
  } while (0)

// Convert buffers to bf16 fragments and run the 16 MFMAs.
#define CVT_MFMA(BA, BB)                                                       \
  do {                                                                         \
    bf16x8 af_[4], bfr_[4];                                                    \
    _Pragma("unroll") for (int m_ = 0; m_ < 4; ++m_)                           \
        _Pragma("unroll") for (int j_ = 0; j_ < 4; ++j_) {                     \
      af_[m_][j_]     = f2bf(BA[m_][0][j_]);                                   \
      af_[m_][4 + j_] = f2bf(BA[m_][1][j_]);                                   \
    }                                                                          \
    _Pragma("unroll") for (int n_ = 0; n_ < 4; ++n_)                           \
        _Pragma("unroll") for (int j_ = 0; j_ < 8; ++j_)                       \
            bfr_[n_][j_] = f2bf(BB[n_][j_]);                                   \
    _Pragma("unroll") for (int m_ = 0; m_ < 4; ++m_)                           \
        _Pragma("unroll") for (int n_ = 0; n_ < 4; ++n_)                       \
            acc[m_][n_] = __builtin_amdgcn_mfma_f32_16x16x32_bf16(             \
                af_[m_], bfr_[n_], acc[m_][n_], 0, 0, 0);                      \
  } while (0)

__global__ __launch_bounds__(256, 2) void mp_gemm(const float* __restrict__ doc,
                                                  const float* __restrict__ emap,
                                                  const float* __restrict__ lens,
                                                  float* __restrict__ out) {
  __shared__ float red[KSPLIT][64 * 64];  // 64 KB fp32 partials

  int bid = (int)blockIdx.x;
  // XCD-chunk swizzle: 512 blocks, 8 XCDs -> XCD x gets logical [64x, 64x+63]
  int logical = (bid & 7) * 64 + (bid >> 3);
  int b  = logical >> 5;        // 16 batches (2 per XCD chunk)
  int et = (logical >> 3) & 3;  // 4 e-tiles of 64 rows
  int dt = logical & 7;         // 8 d-tiles of 64 cols

  int tid  = (int)threadIdx.x;
  int w    = tid >> 6;          // wave 0..3 = K-split index
  int lane = tid & 63;
  int l15  = lane & 15;
  int g    = lane >> 4;         // k-group 0..3

  const float* Ab = emap + (size_t)(b * NE + et * 64) * NL;  // [64][L], k-contig
  const float* Bb = doc  + (size_t)b * NL * ND + dt * 64;    // [L][64], k-major

  int kbase = w * KPW;

  // Per-lane base pointers (A: row = 16m+l15 at k=kbase+8g; B: col = 16n+l15)
  const float* aPtr[4];
  const float* bPtr[4];
#pragma unroll
  for (int m = 0; m < 4; ++m)
    aPtr[m] = Ab + (size_t)(16 * m + l15) * NL + kbase + 8 * g;
#pragma unroll
  for (int n = 0; n < 4; ++n)
    bPtr[n] = Bb + (size_t)(kbase + 8 * g) * ND + 16 * n + l15;

  f32x4 acc[4][4] = {};  // acc[m][n], rows 4g..4g+3, col l15

  f32x4 A0[4][2], A1[4][2];
  float B0[4][8], B1[4][8];

  LOAD_ITER(A0, B0, 0);  // prologue

#pragma unroll 1
  for (int it = 0; it < KITER; it += 2) {
    LOAD_ITER(A1, B1, it + 1);   // issue next loads first (KITER even -> safe)
    CVT_MFMA(A0, B0);            // consume current (waits only on A0/B0)
    if (it + 2 < KITER) LOAD_ITER(A0, B0, it + 2);
    CVT_MFMA(A1, B1);
  }

  // Write fp32 partials to LDS. C/D frag: row = 16m+4g+i, col = 16n+l15.
#pragma unroll
  for (int m = 0; m < 4; ++m)
#pragma unroll
    for (int n = 0; n < 4; ++n)
#pragma unroll
      for (int i = 0; i < 4; ++i)
        red[w][(16 * m + 4 * g + i) * 64 + 16 * n + l15] = acc[m][n][i];

  __syncthreads();

  // Cross-wave reduce + divide + store: 256 threads x 16 passes over 64x64.
  const float* lb = lens + b * NE + et * 64;
  float* ob = out + (size_t)(b * NE + et * 64) * ND + dt * 64;
#pragma unroll
  for (int p = 0; p < 16; ++p) {
    int idx = p * 256 + tid;
    float s = red[0][idx] + red[1][idx] + red[2][idx] + red[3][idx];
    int row = idx >> 6;
    int col = idx & 63;
    ob[(size_t)row * ND + col] = s / lb[row];
  }
}

extern "C" void kernel_launch(void* const* d_in, const int* in_sizes, int n_in,
                              void* d_out, int out_size, void* d_ws, size_t ws_size,
                              hipStream_t stream) {
  const float* doc  = (const float*)d_in[0];  // (B, L, D)
  const float* emap = (const float*)d_in[1];  // (B, E, L)
  const float* lens = (const float*)d_in[2];  // (B, E)
  float* out = (float*)d_out;                 // (B, E, D)
  hipLaunchKernelGGL(mp_gemm, dim3(512), dim3(256), 0, stream, doc, emap, lens, out);
}